// Round 3
// 726.733 us; speedup vs baseline: 1.0086x; 1.0086x over previous
//
#include <hip/hip_runtime.h>

// FlowComposite: iterative flow composition.
// flows: [B, T, 2, H, W] fp32.  out: [B, 2, H, W] fp32.
//
// Hard-won constraints (4 failed experiments):
//  - R1 loop body is bit-exact vs the numpy reference (absmax 0.0). The
//    12-step feedback chain is chaotic: ~1 ulp of rounding change anywhere
//    amplifies to ~0.4 absmax (threshold 0.2525).
//  - R2/R3 (4-chain restructure): FAIL 0.457. R5 (pair-load + PPT=2):
//    FAIL 0.39. R6 (pair-load only, PPT=1, asm-barriered bit-identical
//    corner selects): FAIL 0.427. Conclusion: ANY edit touching the
//    loop-body dataflow -- even provably value-identical load
//    restructuring -- perturbs FP codegen and fails. The loop body below
//    must remain BYTE-IDENTICAL to R1. Only pure index-mapping changes
//    outside the loop are admissible (R4's XCD swizzle passed).
//
// R7 (this version): mapping-class change only -- 2D lane tiling.
//   Counters (R4): 353 us/dispatch, HBM 8.4%, VALU 24%, Occ 87% =>
//   limiter is gather-transaction throughput (TA/L1). A wave currently
//   covers a 64x1 strip: each gather spans ~65 contiguous floats (~3
//   cache lines) x ~5-8 scattered y-rows => ~15-21 line txns/gather.
//   New mapping: wave covers a 16x4 patch (block = 16x16 tile, 4 waves
//   stacked in y): x-span/row ~24 floats (~1.4 lines), rows 4+spread =>
//   ~13-14 txns/gather late, ~5 early. Also: block 2-channel footprint
//   ~4 KB => 8 resident blocks ~ fit 32 KB L1 (better reuse if
//   L2-latency co-limits).
//   Grid unchanged: 16320 = 8 batches x 2040 blocks (60x34 tiles);
//   XCD swizzle retained -> each XCD still works exactly one batch
//   (4.18 MB/t-slice ~ one XCD's 4 MiB L2).

#define FC_B 8
#define FC_T 12
#define FC_H 544
#define FC_W 960

__global__ __launch_bounds__(256) void FlowComposite_kernel(
    const float* __restrict__ flows, float* __restrict__ out)
{
    const int HW = FC_H * FC_W;

    // ---- integer preamble (mapping only; admissible class) ----
    // XCD swizzle identical to R4: physical blockIdx%8 ~ XCD id.
    int p = blockIdx.x;
    int L = (p & 7) * (gridDim.x >> 3) + (p >> 3);   // logical block

    int b    = L / 2040;             // batch: 2040 blocks per batch
    int tile = L - b * 2040;         // tile within batch, 0..2039
    int tileY = tile / 60;           // 60 tiles across (960/16)
    int tileX = tile - tileY * 60;   // 34 tiles down   (544/16)

    int tid = (int)threadIdx.x;
    int x = tileX * 16 + (tid & 15);     // wave = 16x4 patch
    int y = tileY * 16 + (tid >> 4);     // block = 16x16 patch

    // ---- loop body: BYTE-IDENTICAL to R1/R4. DO NOT TOUCH. ----
    float u = 0.0f, v = 0.0f;
    const float* fb = flows + (size_t)b * FC_T * 2 * HW;

    #pragma unroll 1
    for (int t = 0; t < FC_T; ++t) {
        const float* f0 = fb + (size_t)t * 2 * HW;   // channel 0 (dx)
        const float* f1 = f0 + HW;                   // channel 1 (dy)

        float px = (float)x + u - 0.5f;
        float py = (float)y + v - 0.5f;

        float x0f = floorf(px);
        float y0f = floorf(py);
        float wx1 = px - x0f;
        float wx0 = 1.0f - wx1;
        float wy1 = py - y0f;
        float wy0 = 1.0f - wy1;

        int x0 = (int)x0f;
        int y0 = (int)y0f;
        int x1 = x0 + 1;
        int y1 = y0 + 1;

        // zeros padding: validity folded into weights (branchless)
        float vx0 = (x0 >= 0 && x0 < FC_W) ? 1.0f : 0.0f;
        float vx1 = (x1 >= 0 && x1 < FC_W) ? 1.0f : 0.0f;
        float vy0 = (y0 >= 0 && y0 < FC_H) ? 1.0f : 0.0f;
        float vy1 = (y1 >= 0 && y1 < FC_H) ? 1.0f : 0.0f;

        int x0c = min(max(x0, 0), FC_W - 1);
        int x1c = min(max(x1, 0), FC_W - 1);
        int y0c = min(max(y0, 0), FC_H - 1);
        int y1c = min(max(y1, 0), FC_H - 1);

        float w00 = wx0 * wy0 * vx0 * vy0;
        float w10 = wx1 * wy0 * vx1 * vy0;
        float w01 = wx0 * wy1 * vx0 * vy1;
        float w11 = wx1 * wy1 * vx1 * vy1;

        int i00 = y0c * FC_W + x0c;
        int i10 = y0c * FC_W + x1c;
        int i01 = y1c * FC_W + x0c;
        int i11 = y1c * FC_W + x1c;

        float s0 = w00 * f0[i00] + w10 * f0[i10] + w01 * f0[i01] + w11 * f0[i11];
        float s1 = w00 * f1[i00] + w10 * f1[i10] + w01 * f1[i01] + w11 * f1[i11];

        u += s0;
        v += s1;
    }

    size_t ob = (size_t)b * 2 * HW + (size_t)y * FC_W + x;
    out[ob]      = u;   // channel 0
    out[ob + HW] = v;   // channel 1
}

extern "C" void kernel_launch(void* const* d_in, const int* in_sizes, int n_in,
                              void* d_out, int out_size, void* d_ws, size_t ws_size,
                              hipStream_t stream) {
    const float* flows = (const float*)d_in[0];
    float* out = (float*)d_out;

    const int N = FC_B * FC_H * FC_W;    // 4,177,920
    dim3 block(256);
    dim3 grid(N / 256);                  // 16320 = 8 XCDs x 2040 blocks
    hipLaunchKernelGGL(FlowComposite_kernel, grid, block, 0, stream, flows, out);
}